// Round 2
// baseline (1296.785 us; speedup 1.0000x reference)
//
#include <hip/hip_runtime.h>
#include <hip/hip_bf16.h>

#define Bn 2
#define Tn 12
#define Hn 80
#define Wn 120
#define CIN 6
#define Fn 32
#define PXG 15   // pixels per thread

__device__ __forceinline__ float fast_sigmoid(float v) {
    return 1.f / (1.f + __expf(-v));   // v->-inf: 1/inf = 0, no NaN
}
__device__ __forceinline__ float fast_tanh(float v) {
    v = fminf(fmaxf(v, -15.f), 15.f);
    float e = __expf(2.f * v);
    return (e - 1.f) / (e + 1.f);
}

// grid: dir(2) * b(2) * y(80) * half(2) = 640 blocks, 256 threads
// thread: c = gate channel 0..63 (z: 0..31 -> Wx/Wzr col c; r: 32..63), g = pixel group 0..3
__global__ __launch_bounds__(256) void gates_kernel(
    const float* __restrict__ x,
    const float* __restrict__ Wx_f, const float* __restrict__ b_f, const float* __restrict__ Wzr_f,
    const float* __restrict__ Wx_b, const float* __restrict__ b_b, const float* __restrict__ Wzr_b,
    const float* __restrict__ hprev,   // [dir][b][y][x][32] fp32, valid when s>0
    float* __restrict__ wz, float* __restrict__ wrh, int s)
{
    int tid  = threadIdx.x;
    int c    = tid & 63;
    int g    = tid >> 6;        // 0..3
    int bid  = blockIdx.x;
    int half = bid & 1;
    int r    = bid >> 1;
    int y    = r % Hn;
    int b    = (r / Hn) % Bn;
    int dir  = r / (Hn * Bn);
    int x0   = (half * 4 + g) * PXG;   // 0..105

    const float* Wx  = dir ? Wx_b  : Wx_f;
    const float* bia = dir ? b_b   : b_f;
    const float* Wzr = dir ? Wzr_b : Wzr_f;
    int t = dir ? (Tn - 1 - s) : s;
    bool first = (s == 0);

    float acc[PXG];
    float bv = bia[c];
    #pragma unroll
    for (int j = 0; j < PXG; j++) acc[j] = bv;

    bool lok = (x0 > 0);
    bool rok = (x0 + PXG < Wn);

    // ---- input conv: xz (c<32) / xr (c>=32); Wx col = c ----
    for (int ky = 0; ky < 3; ky++) {
        int iy = y + ky - 1;
        if (iy < 0 || iy >= Hn) continue;
        const float* xrow = x + (size_t)(((b * Tn + t) * Hn + iy) * Wn) * CIN;
        const float* wk = Wx + (ky * 3 * CIN) * 96 + c;
        #pragma unroll
        for (int ci = 0; ci < CIN; ci++) {
            float w0 = wk[ci * 96];
            float w1 = wk[(CIN + ci) * 96];
            float w2 = wk[(2 * CIN + ci) * 96];
            const float* xr = xrow + ci;
            float a  = lok ? xr[(x0 - 1) * CIN] : 0.f;
            float bb = xr[x0 * CIN];
            #pragma unroll
            for (int j = 0; j < PXG; j++) {
                float cc;
                if (j == PXG - 1) cc = rok ? xr[(x0 + PXG) * CIN] : 0.f;
                else              cc = xr[(x0 + j + 1) * CIN];
                acc[j] += a * w0 + bb * w1 + cc * w2;
                a = bb; bb = cc;
            }
        }
    }

    // ---- recurrent conv over h_prev (fp32): Wzr col = c ----
    if (!first) {
        const float* hb = hprev + (size_t)(((dir * Bn + b) * Hn) * Wn) * Fn;
        for (int ky = 0; ky < 3; ky++) {
            int iy = y + ky - 1;
            if (iy < 0 || iy >= Hn) continue;
            const float* hrow = hb + (size_t)iy * Wn * Fn;
            const float* wk = Wzr + (ky * 3 * Fn) * 64 + c;
            #pragma unroll 4
            for (int ci = 0; ci < Fn; ci++) {
                float w0 = wk[ci * 64];
                float w1 = wk[(Fn + ci) * 64];
                float w2 = wk[(2 * Fn + ci) * 64];
                const float* hr = hrow + ci;
                float a  = lok ? hr[(x0 - 1) * Fn] : 0.f;
                float bb = hr[x0 * Fn];
                #pragma unroll
                for (int j = 0; j < PXG; j++) {
                    float cc;
                    if (j == PXG - 1) cc = rok ? hr[(x0 + PXG) * Fn] : 0.f;
                    else              cc = hr[(x0 + j + 1) * Fn];
                    acc[j] += a * w0 + bb * w1 + cc * w2;
                    a = bb; bb = cc;
                }
            }
        }
    }

    // ---- epilogue: z -> wz ; r*h_center -> wrh ----
    int pbase = ((dir * Bn + b) * Hn + y) * Wn;
    int c32 = c & (Fn - 1);
    const float* hcen = hprev + (size_t)pbase * Fn + c32;
    if (c < Fn) {
        #pragma unroll
        for (int j = 0; j < PXG; j++) {
            float zg = fast_sigmoid(acc[j]);
            wz[(size_t)(pbase + x0 + j) * Fn + c32] = zg;
        }
    } else {
        #pragma unroll
        for (int j = 0; j < PXG; j++) {
            float rg = fast_sigmoid(acc[j]);
            float hc = first ? 0.f : hcen[(size_t)(x0 + j) * Fn];
            wrh[(size_t)(pbase + x0 + j) * Fn + c32] = rg * hc;
        }
    }
}

// grid: 640 blocks, 128 threads; thread: c = 0..31, g = 0..3
__global__ __launch_bounds__(128) void update_kernel(
    const float* __restrict__ x,
    const float* __restrict__ Wx_f, const float* __restrict__ b_f, const float* __restrict__ Wh_f,
    const float* __restrict__ Wx_b, const float* __restrict__ b_b, const float* __restrict__ Wh_b,
    const float* __restrict__ hprev, float* __restrict__ hcur,
    const float* __restrict__ wz, const float* __restrict__ wrh,
    float* __restrict__ out, int s)
{
    int tid  = threadIdx.x;
    int c    = tid & 31;
    int g    = tid >> 5;       // 0..3
    int bid  = blockIdx.x;
    int half = bid & 1;
    int r    = bid >> 1;
    int y    = r % Hn;
    int b    = (r / Hn) % Bn;
    int dir  = r / (Hn * Bn);
    int x0   = (half * 4 + g) * PXG;

    const float* Wx  = dir ? Wx_b : Wx_f;
    const float* bia = dir ? b_b  : b_f;
    const float* Wh  = dir ? Wh_b : Wh_f;
    int t = dir ? (Tn - 1 - s) : s;
    bool first = (s == 0);

    float acc[PXG];
    float bv = bia[64 + c];
    #pragma unroll
    for (int j = 0; j < PXG; j++) acc[j] = bv;

    bool lok = (x0 > 0);
    bool rok = (x0 + PXG < Wn);

    // ---- input conv: xh; Wx col = 64 + c ----
    for (int ky = 0; ky < 3; ky++) {
        int iy = y + ky - 1;
        if (iy < 0 || iy >= Hn) continue;
        const float* xrow = x + (size_t)(((b * Tn + t) * Hn + iy) * Wn) * CIN;
        const float* wk = Wx + (ky * 3 * CIN) * 96 + 64 + c;
        #pragma unroll
        for (int ci = 0; ci < CIN; ci++) {
            float w0 = wk[ci * 96];
            float w1 = wk[(CIN + ci) * 96];
            float w2 = wk[(2 * CIN + ci) * 96];
            const float* xr = xrow + ci;
            float a  = lok ? xr[(x0 - 1) * CIN] : 0.f;
            float bb = xr[x0 * CIN];
            #pragma unroll
            for (int j = 0; j < PXG; j++) {
                float cc;
                if (j == PXG - 1) cc = rok ? xr[(x0 + PXG) * CIN] : 0.f;
                else              cc = xr[(x0 + j + 1) * CIN];
                acc[j] += a * w0 + bb * w1 + cc * w2;
                a = bb; bb = cc;
            }
        }
    }

    // ---- conv over rh (fp32): Wh col = c ----
    {
        const float* rb = wrh + (size_t)(((dir * Bn + b) * Hn) * Wn) * Fn;
        for (int ky = 0; ky < 3; ky++) {
            int iy = y + ky - 1;
            if (iy < 0 || iy >= Hn) continue;
            const float* rrow = rb + (size_t)iy * Wn * Fn;
            const float* wk = Wh + (ky * 3 * Fn) * Fn + c;
            #pragma unroll 4
            for (int ci = 0; ci < Fn; ci++) {
                float w0 = wk[ci * Fn];
                float w1 = wk[(Fn + ci) * Fn];
                float w2 = wk[(2 * Fn + ci) * Fn];
                const float* rr = rrow + ci;
                float a  = lok ? rr[(x0 - 1) * Fn] : 0.f;
                float bb = rr[x0 * Fn];
                #pragma unroll
                for (int j = 0; j < PXG; j++) {
                    float cc;
                    if (j == PXG - 1) cc = rok ? rr[(x0 + PXG) * Fn] : 0.f;
                    else              cc = rr[(x0 + j + 1) * Fn];
                    acc[j] += a * w0 + bb * w1 + cc * w2;
                    a = bb; bb = cc;
                }
            }
        }
    }

    // ---- epilogue: h = z*h_prev + (1-z)*tanh(acc) ----
    int pbase = ((dir * Bn + b) * Hn + y) * Wn;
    const float* hc_p = hprev + (size_t)pbase * Fn + c;
    float*       hw   = hcur  + (size_t)pbase * Fn + c;
    const float* zp   = wz    + (size_t)pbase * Fn + c;
    float* ob = out + (size_t)(((b * Tn + t) * Hn + y) * Wn) * 64 + dir * Fn + c;
    #pragma unroll
    for (int j = 0; j < PXG; j++) {
        float hh = fast_tanh(acc[j]);
        float z  = zp[(size_t)(x0 + j) * Fn];
        float hp = first ? 0.f : hc_p[(size_t)(x0 + j) * Fn];
        float hn = z * hp + (1.f - z) * hh;
        hw[(size_t)(x0 + j) * Fn] = hn;
        ob[(size_t)(x0 + j) * 64] = hn;
    }
}

extern "C" void kernel_launch(void* const* d_in, const int* in_sizes, int n_in,
                              void* d_out, int out_size, void* d_ws, size_t ws_size,
                              hipStream_t stream)
{
    const float* x     = (const float*)d_in[0];
    const float* Wx_f  = (const float*)d_in[1];
    const float* b_f   = (const float*)d_in[2];
    const float* Wzr_f = (const float*)d_in[3];
    const float* Wh_f  = (const float*)d_in[4];
    const float* Wx_b  = (const float*)d_in[5];
    const float* b_b   = (const float*)d_in[6];
    const float* Wzr_b = (const float*)d_in[7];
    const float* Wh_b  = (const float*)d_in[8];
    float* out = (float*)d_out;

    float* ws = (float*)d_ws;
    const size_t HSLOT = (size_t)2 * Bn * Hn * Wn * Fn;  // 1,228,800 floats per h slot (both dirs)
    float* h0  = ws;
    float* h1  = ws + HSLOT;
    float* wzb = ws + 2 * HSLOT;
    float* wrb = ws + 3 * HSLOT;   // total ws use: 4*HSLOT*4B = 19.7 MB

    for (int s = 0; s < Tn; s++) {
        float* hprev = (s & 1) ? h0 : h1;  // slot (s-1)&1 ; unused (guarded) at s==0
        float* hcur  = (s & 1) ? h1 : h0;  // slot s&1
        gates_kernel<<<640, 256, 0, stream>>>(x, Wx_f, b_f, Wzr_f, Wx_b, b_b, Wzr_b,
                                              hprev, wzb, wrb, s);
        update_kernel<<<640, 128, 0, stream>>>(x, Wx_f, b_f, Wh_f, Wx_b, b_b, Wh_b,
                                               hprev, hcur, wzb, wrb, out, s);
    }
}

// Round 3
// 438.123 us; speedup vs baseline: 2.9599x; 2.9599x over previous
//
#include <hip/hip_runtime.h>
#include <hip/hip_bf16.h>

#define Bn 2
#define Tn 12
#define Hn 80
#define Wn 120
#define CIN 6
#define Fn 32

#define BH_ROW 296   // shorts per LDS weight row: 288 data + 8 pad (592 B -> 2-way banks, free)

typedef __attribute__((ext_vector_type(8))) short short8;
typedef __attribute__((ext_vector_type(4))) float f32x4;

__device__ __forceinline__ short f2bf(float f) {
    union { __hip_bfloat16 h; short s; } u;
    u.h = __float2bfloat16(f);
    return u.s;
}
__device__ __forceinline__ float fast_sigmoid(float v) { return 1.f / (1.f + __expf(-v)); }
__device__ __forceinline__ float fast_tanh(float v) {
    v = fminf(fmaxf(v, -15.f), 15.f);
    float e = __expf(2.f * v);
    return (e - 1.f) / (e + 1.f);
}

// ---- one-time weight pack: transpose to [dir][n][k] bf16 (+ zero-padded x-taps) ----
// wzrP: [2][64][288]  whP: [2][32][288]  wxgP: [2][9][64][8]  wxhP: [2][9][32][8]
__global__ __launch_bounds__(256) void pack_weights(
    const float* __restrict__ Wzr_f, const float* __restrict__ Wzr_b,
    const float* __restrict__ Wh_f,  const float* __restrict__ Wh_b,
    const float* __restrict__ Wx_f,  const float* __restrict__ Wx_b,
    short* __restrict__ wzrP, short* __restrict__ whP,
    short* __restrict__ wxgP, short* __restrict__ wxhP)
{
    int i = blockIdx.x * 256 + threadIdx.x;
    const int SZR = 2 * 64 * 288;
    const int SWH = 2 * 32 * 288;
    const int SXG = 2 * 9 * 64 * 8;
    const int SXH = 2 * 9 * 32 * 8;
    if (i < SZR) {
        int dir = i / (64 * 288); int r = i % (64 * 288);
        int nn = r / 288, k = r % 288;
        const float* W = dir ? Wzr_b : Wzr_f;          // [tap][ci][64]
        wzrP[i] = f2bf(W[k * 64 + nn]);
    } else if (i < SZR + SWH) {
        int j = i - SZR;
        int dir = j / (32 * 288); int r = j % (32 * 288);
        int nn = r / 288, k = r % 288;
        const float* W = dir ? Wh_b : Wh_f;            // [tap][ci][32]
        whP[j] = f2bf(W[k * 32 + nn]);
    } else if (i < SZR + SWH + SXG) {
        int j = i - SZR - SWH;
        int dir = j / (9 * 64 * 8); int r = j % (9 * 64 * 8);
        int tap = r / 512; int q2 = r % 512; int nn = q2 / 8; int jj = q2 % 8;
        const float* W = dir ? Wx_b : Wx_f;            // [tap][ci6][96]
        wxgP[j] = (jj < 6) ? f2bf(W[(tap * 6 + jj) * 96 + nn]) : (short)0;
    } else if (i < SZR + SWH + SXG + SXH) {
        int j = i - SZR - SWH - SXG;
        int dir = j / (9 * 32 * 8); int r = j % (9 * 32 * 8);
        int tap = r / 256; int q2 = r % 256; int nn = q2 / 8; int jj = q2 % 8;
        const float* W = dir ? Wx_b : Wx_f;
        wxhP[j] = (jj < 6) ? f2bf(W[(tap * 6 + jj) * 96 + 64 + nn]) : (short)0;
    }
}

// grid 640 = dir(2) x b(2) x yblk(20) x seg(8); 256 thr = 4 waves = 4 consecutive y
// wave computes 16px x 64 gates via MFMA 16x16x32 bf16, K = 9 h-chunks + 9 x-chunks
__global__ __launch_bounds__(256) void gates_mfma(
    const float* __restrict__ x,
    const float* __restrict__ b_f, const float* __restrict__ b_b,
    const short* __restrict__ wzrP, const short* __restrict__ wxgP,
    const short* __restrict__ hbf,     // h bf16 [dir][b][y][px][32]
    const float* __restrict__ hprevf,  // h fp32 (prev slot)
    float* __restrict__ wz, short* __restrict__ rhb, int s)
{
    __shared__ short lds[64 * BH_ROW + 9 * 64 * 8];
    int tid = threadIdx.x;
    int bid = blockIdx.x;
    int seg = bid & 7;
    int t1  = bid >> 3;
    int yb  = t1 % 20;
    int t2  = t1 / 20;
    int b   = t2 & 1;
    int dir = t2 >> 1;

    // stage packed weights into LDS (Bh: 64 rows x 36 chunks, Bx: 9*64 chunks)
    const short* wsrc = wzrP + dir * 64 * 288;
    const short* xsrc = wxgP + dir * 9 * 64 * 8;
    for (int i = tid; i < 64 * 36 + 9 * 64; i += 256) {
        if (i < 64 * 36) {
            int nn = i / 36, c = i % 36;
            *(uint4*)&lds[nn * BH_ROW + c * 8] = *(const uint4*)&wsrc[nn * 288 + c * 8];
        } else {
            int j = i - 64 * 36;
            *(uint4*)&lds[64 * BH_ROW + j * 8] = *(const uint4*)&xsrc[j * 8];
        }
    }
    __syncthreads();

    int wid = tid >> 6, lane = tid & 63;
    int n = lane & 15, q = lane >> 4;
    int q8 = q * 8;
    int y  = yb * 4 + wid;
    int x0 = seg * 16;
    int t  = dir ? (Tn - 1 - s) : s;

    const short* hslab = hbf + (size_t)(dir * Bn + b) * Hn * Wn * Fn;
    const float* xslab = x + (size_t)((b * Tn + t) * Hn) * Wn * CIN;

    f32x4 acc[4];
    #pragma unroll
    for (int nt = 0; nt < 4; nt++) acc[nt] = (f32x4)0.f;

    for (int ky = 0; ky < 3; ky++) {
        int iy = y + ky - 1;
        if (iy < 0 || iy >= Hn) continue;
        #pragma unroll
        for (int kx = 0; kx < 3; kx++) {
            int tap = ky * 3 + kx;
            int px = x0 + n + kx - 1;
            bool pok = (px >= 0 && px < Wn);
            // ---- x chunk (6 real channels, zero-padded to K=32; data in quad 0 only) ----
            short8 ax = (short8)(short)0;
            if (q == 0 && pok) {
                const float* xp = xslab + ((size_t)iy * Wn + px) * CIN;
                ax[0] = f2bf(xp[0]); ax[1] = f2bf(xp[1]); ax[2] = f2bf(xp[2]);
                ax[3] = f2bf(xp[3]); ax[4] = f2bf(xp[4]); ax[5] = f2bf(xp[5]);
            }
            #pragma unroll
            for (int nt = 0; nt < 4; nt++) {
                short8 bx = (short8)(short)0;
                if (q == 0) bx = *(const short8*)&lds[64 * BH_ROW + (tap * 64 + nt * 16 + n) * 8];
                acc[nt] = __builtin_amdgcn_mfma_f32_16x16x32_bf16(ax, bx, acc[nt], 0, 0, 0);
            }
            // ---- h chunk (32 channels) ----
            if (s > 0) {
                short8 ah = (short8)(short)0;
                if (pok) ah = *(const short8*)&hslab[((size_t)iy * Wn + px) * Fn + q8];
                #pragma unroll
                for (int nt = 0; nt < 4; nt++) {
                    short8 bh = *(const short8*)&lds[(nt * 16 + n) * BH_ROW + tap * 32 + q8];
                    acc[nt] = __builtin_amdgcn_mfma_f32_16x16x32_bf16(ah, bh, acc[nt], 0, 0, 0);
                }
            }
        }
    }

    // ---- epilogue: D row(m=pixel)=q*4+r, col(gate)=nt*16+n ----
    const float* bias = dir ? b_b : b_f;
    size_t pbase = ((size_t)(dir * Bn + b) * Hn + y) * Wn;
    #pragma unroll
    for (int nt = 0; nt < 4; nt++) {
        int g = nt * 16 + n;
        float bg = bias[g];
        #pragma unroll
        for (int r = 0; r < 4; r++) {
            int px = x0 + q * 4 + r;
            if (px >= Wn) continue;
            float v = fast_sigmoid(acc[nt][r] + bg);
            size_t pidx = (pbase + px) * Fn;
            if (nt < 2) {
                wz[pidx + g] = v;                      // z gate
            } else {
                int c = g - 32;                        // r gate
                float hp = (s > 0) ? hprevf[pidx + c] : 0.f;
                rhb[pidx + c] = f2bf(v * hp);
            }
        }
    }
}

// wave computes 16px x 32 candidate channels; A = rh (bf16), B = Wh + Wx[:,64:96]
__global__ __launch_bounds__(256) void update_mfma(
    const float* __restrict__ x,
    const float* __restrict__ b_f, const float* __restrict__ b_b,
    const short* __restrict__ whP, const short* __restrict__ wxhP,
    const short* __restrict__ rhb,
    const float* __restrict__ hprevf, float* __restrict__ hcurf,
    short* __restrict__ hbf, const float* __restrict__ wz,
    float* __restrict__ out, int s)
{
    __shared__ short lds2[32 * BH_ROW + 9 * 32 * 8];
    int tid = threadIdx.x;
    int bid = blockIdx.x;
    int seg = bid & 7;
    int t1  = bid >> 3;
    int yb  = t1 % 20;
    int t2  = t1 / 20;
    int b   = t2 & 1;
    int dir = t2 >> 1;

    const short* wsrc = whP + dir * 32 * 288;
    const short* xsrc = wxhP + dir * 9 * 32 * 8;
    for (int i = tid; i < 32 * 36 + 9 * 32; i += 256) {
        if (i < 32 * 36) {
            int nn = i / 36, c = i % 36;
            *(uint4*)&lds2[nn * BH_ROW + c * 8] = *(const uint4*)&wsrc[nn * 288 + c * 8];
        } else {
            int j = i - 32 * 36;
            *(uint4*)&lds2[32 * BH_ROW + j * 8] = *(const uint4*)&xsrc[j * 8];
        }
    }
    __syncthreads();

    int wid = tid >> 6, lane = tid & 63;
    int n = lane & 15, q = lane >> 4;
    int q8 = q * 8;
    int y  = yb * 4 + wid;
    int x0 = seg * 16;
    int t  = dir ? (Tn - 1 - s) : s;

    const short* rslab = rhb + (size_t)(dir * Bn + b) * Hn * Wn * Fn;
    const float* xslab = x + (size_t)((b * Tn + t) * Hn) * Wn * CIN;

    f32x4 acc[2];
    acc[0] = (f32x4)0.f; acc[1] = (f32x4)0.f;

    for (int ky = 0; ky < 3; ky++) {
        int iy = y + ky - 1;
        if (iy < 0 || iy >= Hn) continue;
        #pragma unroll
        for (int kx = 0; kx < 3; kx++) {
            int tap = ky * 3 + kx;
            int px = x0 + n + kx - 1;
            bool pok = (px >= 0 && px < Wn);
            // x chunk
            short8 ax = (short8)(short)0;
            if (q == 0 && pok) {
                const float* xp = xslab + ((size_t)iy * Wn + px) * CIN;
                ax[0] = f2bf(xp[0]); ax[1] = f2bf(xp[1]); ax[2] = f2bf(xp[2]);
                ax[3] = f2bf(xp[3]); ax[4] = f2bf(xp[4]); ax[5] = f2bf(xp[5]);
            }
            #pragma unroll
            for (int nt = 0; nt < 2; nt++) {
                short8 bx = (short8)(short)0;
                if (q == 0) bx = *(const short8*)&lds2[32 * BH_ROW + (tap * 32 + nt * 16 + n) * 8];
                acc[nt] = __builtin_amdgcn_mfma_f32_16x16x32_bf16(ax, bx, acc[nt], 0, 0, 0);
            }
            // rh chunk (rh is written for all px every step, zeros at s==0)
            {
                short8 ah = (short8)(short)0;
                if (pok) ah = *(const short8*)&rslab[((size_t)iy * Wn + px) * Fn + q8];
                #pragma unroll
                for (int nt = 0; nt < 2; nt++) {
                    short8 bh = *(const short8*)&lds2[(nt * 16 + n) * BH_ROW + tap * 32 + q8];
                    acc[nt] = __builtin_amdgcn_mfma_f32_16x16x32_bf16(ah, bh, acc[nt], 0, 0, 0);
                }
            }
        }
    }

    // epilogue: h_new = z*h_prev + (1-z)*tanh(xh + conv(rh))
    const float* bias = dir ? b_b : b_f;
    size_t pbase = ((size_t)(dir * Bn + b) * Hn + y) * Wn;
    #pragma unroll
    for (int nt = 0; nt < 2; nt++) {
        int c = nt * 16 + n;
        float bg = bias[64 + c];
        #pragma unroll
        for (int r = 0; r < 4; r++) {
            int px = x0 + q * 4 + r;
            if (px >= Wn) continue;
            float v = fast_tanh(acc[nt][r] + bg);
            size_t pidx = (pbase + px) * Fn;
            float z = wz[pidx + c];
            float hp = (s > 0) ? hprevf[pidx + c] : 0.f;
            float hn = z * hp + (1.f - z) * v;
            hcurf[pidx + c] = hn;
            hbf[pidx + c] = f2bf(hn);
            out[(((size_t)(b * Tn + t) * Hn + y) * Wn + px) * 64 + dir * Fn + c] = hn;
        }
    }
}

extern "C" void kernel_launch(void* const* d_in, const int* in_sizes, int n_in,
                              void* d_out, int out_size, void* d_ws, size_t ws_size,
                              hipStream_t stream)
{
    const float* x     = (const float*)d_in[0];
    const float* Wx_f  = (const float*)d_in[1];
    const float* b_f   = (const float*)d_in[2];
    const float* Wzr_f = (const float*)d_in[3];
    const float* Wh_f  = (const float*)d_in[4];
    const float* Wx_b  = (const float*)d_in[5];
    const float* b_b   = (const float*)d_in[6];
    const float* Wzr_b = (const float*)d_in[7];
    const float* Wh_b  = (const float*)d_in[8];
    float* out = (float*)d_out;

    const size_t HS = (size_t)2 * Bn * Hn * Wn * Fn;   // 1,228,800 elements per field
    float* h0f = (float*)d_ws;
    float* h1f = h0f + HS;
    float* wzb = h1f + HS;
    short* hbf  = (short*)(wzb + HS);
    short* rhb  = hbf + HS;
    short* wzrP = rhb + HS;            // 36864
    short* whP  = wzrP + 2 * 64 * 288; // 18432
    short* wxgP = whP + 2 * 32 * 288;  // 9216
    short* wxhP = wxgP + 2 * 9 * 64 * 8; // 4608
    // total ws: 3*4.9MB fp32 + 2*2.46MB bf16 + 138KB weights = 19.8 MB

    pack_weights<<<270, 256, 0, stream>>>(Wzr_f, Wzr_b, Wh_f, Wh_b, Wx_f, Wx_b,
                                          wzrP, whP, wxgP, wxhP);

    for (int s = 0; s < Tn; s++) {
        float* hprev = (s & 1) ? h0f : h1f;   // slot (s-1)&1, guarded at s==0
        float* hcur  = (s & 1) ? h1f : h0f;   // slot s&1
        gates_mfma<<<640, 256, 0, stream>>>(x, b_f, b_b, wzrP, wxgP,
                                            hbf, hprev, wzb, rhb, s);
        update_mfma<<<640, 256, 0, stream>>>(x, b_f, b_b, whP, wxhP,
                                             rhb, hprev, hcur, hbf, wzb, out, s);
    }
}